// Round 4
// baseline (2704.182 us; speedup 1.0000x reference)
//
#include <hip/hip_runtime.h>
#include <cstdint>
#include <cstddef>

// Problem dims (fixed by reference)
#define B_    64
#define T_    4096
#define H_    128
#define C1_   64
#define NCLS_ 40

typedef _Float16 half2_t __attribute__((ext_vector_type(2)));

__device__ __forceinline__ float fdot2(half2_t a, half2_t b, float c){
#if defined(__has_builtin) && __has_builtin(__builtin_amdgcn_fdot2)
  return __builtin_amdgcn_fdot2(a, b, c, false);   // v_dot2_f32_f16, full-rate
#else
  return fmaf((float)a.x, (float)b.x, fmaf((float)a.y, (float)b.y, c));
#endif
}
__device__ __forceinline__ half2_t bc2(unsigned int u){ return __builtin_bit_cast(half2_t, u); }
__device__ __forceinline__ half2_t pack2(float a, float b){
  half2_t r; r.x = (_Float16)a; r.y = (_Float16)b; return r;   // RTNE
}

// quad_perm DPP cross-lane (VALU pipe). ctrl = l0|l1<<2|l2<<4|l3<<6
template<int CTRL>
__device__ __forceinline__ float qperm(float x){
  return __int_as_float(__builtin_amdgcn_update_dpp(0, __float_as_int(x), CTRL, 0xF, 0xF, true));
}

// ---------------- kernel 1: 3x3 second-moment stats of x over B*T ----------------
__global__ __launch_bounds__(256) void stats_kernel(const float* __restrict__ x,
                                                    float* __restrict__ stats){
  int t = blockIdx.x * 256 + threadIdx.x;
  const float4* xv = (const float4*)x + (size_t)t * 3;
  float4 a = xv[0], b = xv[1], c = xv[2];
  float x0[4] = {a.x, a.w, b.z, c.y};
  float x1[4] = {a.y, b.x, b.w, c.z};
  float x2[4] = {a.z, b.y, c.x, c.w};
  float s[9] = {0,0,0,0,0,0,0,0,0};
  #pragma unroll
  for (int r=0;r<4;++r){
    s[0]+=x0[r]; s[1]+=x1[r]; s[2]+=x2[r];
    s[3]+=x0[r]*x0[r]; s[4]+=x0[r]*x1[r]; s[5]+=x0[r]*x2[r];
    s[6]+=x1[r]*x1[r]; s[7]+=x1[r]*x2[r]; s[8]+=x2[r]*x2[r];
  }
  __shared__ float red[9][256];
  #pragma unroll
  for (int j=0;j<9;++j) red[j][threadIdx.x] = s[j];
  __syncthreads();
  if (threadIdx.x < 9){
    float sum = 0.f;
    for (int i=0;i<256;++i) sum += red[threadIdx.x][i];
    atomicAdd(&stats[threadIdx.x], sum);
  }
}

// Fold conv + BN(train stats) + gamma/beta into per-channel affine. conv_b cancels.
__device__ __forceinline__ void chan_affine(int c, const float* __restrict__ conv_w,
    const float* __restrict__ bn_g, const float* __restrict__ bn_b,
    const float* __restrict__ stats,
    float& A0, float& A1, float& A2, float& Bc){
  const float Ninv = 1.0f / (float)(B_*T_);
  float m0=stats[0]*Ninv, m1=stats[1]*Ninv, m2=stats[2]*Ninv;
  float c00=stats[3]*Ninv-m0*m0, c01=stats[4]*Ninv-m0*m1, c02=stats[5]*Ninv-m0*m2;
  float c11=stats[6]*Ninv-m1*m1, c12=stats[7]*Ninv-m1*m2, c22=stats[8]*Ninv-m2*m2;
  float w0=conv_w[c*3+0], w1=conv_w[c*3+1], w2=conv_w[c*3+2];
  float var = w0*(w0*c00 + 2.f*(w1*c01 + w2*c02)) + w1*(w1*c11 + 2.f*w2*c12) + w2*w2*c22;
  float sc = bn_g[c] * rsqrtf(var + 1e-5f);
  A0 = w0*sc; A1 = w1*sc; A2 = w2*sc;
  Bc = bn_b[c] - (w0*m0 + w1*m1 + w2*m2)*sc;
}

// ---------------- kernel 2: persistent per-batch LSTM ----------------
// 64 blocks x 256 threads (4 waves, 1/SIMD). Thread t: g=t>>2 (k-pair {g, 64+g}),
// w=t&3 (32-wide h window / 16-wide y window). 8 gate-rows/thread, f16 dot2 datapath.
// Quad reduce-scatter (2 select+DPP levels): lane w ends with rows {w&3 (k=g),
// 4+(w&3) (k=64+g)}; activations lane-parallel; two recombines per quad.
__global__ __launch_bounds__(256,1) void lstm_kernel(
    const float* __restrict__ x,
    const float* __restrict__ conv_w, const float* __restrict__ bn_g,
    const float* __restrict__ bn_b, const float* __restrict__ stats,
    const float* __restrict__ w_ih, const float* __restrict__ b_ih,
    const float* __restrict__ b_hh, const float* __restrict__ w_hh,
    const float* __restrict__ h0, const float* __restrict__ c0,
    const float* __restrict__ out_w, const float* __restrict__ out_b,
    float* __restrict__ out){
  int b = blockIdx.x, t = threadIdx.x;
  int g = t >> 2, w = t & 3;
  int yc = t >> 2;                                  // y channel this thread produces ((t&3)==0)
  __shared__ __align__(16) _Float16 hbuf[2][H_];
  __shared__ __align__(16) _Float16 ybuf[2][C1_];

  int kkA = g, kkB = 64 + g;
  // weights: 8 rows (gate=r&3, kk = r<4 ? g : 64+g); h cols [w*32,w*32+32), y cols [w*16,w*16+16)
  half2_t wh[8][16];
  half2_t wy[8][8];
  float bias[8];
  #pragma unroll
  for (int r=0; r<8; ++r){
    int gate = r & 3;
    int kk = (r < 4) ? kkA : kkB;
    const float4* p = (const float4*)(w_hh + (size_t)(gate*H_ + kk)*H_ + w*32);
    #pragma unroll
    for (int i=0;i<8;++i){
      float4 v = p[i];
      wh[r][2*i]   = pack2(v.x, v.y);
      wh[r][2*i+1] = pack2(v.z, v.w);
    }
    const float4* py = (const float4*)(w_ih + (size_t)(gate*H_ + kk)*C1_ + w*16);
    #pragma unroll
    for (int i=0;i<4;++i){
      float4 v = py[i];
      wy[r][2*i]   = pack2(v.x, v.y);
      wy[r][2*i+1] = pack2(v.z, v.w);
    }
    bias[r] = b_ih[gate*H_+kk] + b_hh[gate*H_+kk];
  }
  // unified activation constants for lane gate q=w: sigmoid S=-log2e,A=0,B=1; tanh(G,q==2) S=2log2e,A=1,B=-2
  float S  = (w==2) ?  2.8853900817779268f : -1.4426950408889634f;
  float Aa = (w==2) ?  1.f : 0.f;
  float Bb = (w==2) ? -2.f : 1.f;
  bool o1 = (w & 1) != 0;
  bool o2 = (w & 2) != 0;

  // per-thread y affine coeffs (channel yc, producers are (t&3)==0)
  float ya0, ya1, ya2, ya3;
  chan_affine(yc, conv_w, bn_g, bn_b, stats, ya0, ya1, ya2, ya3);

  // scalar (block-uniform) x pipeline: xs = x[step+1], xn = x[step+2]
  const float* xb = x + (size_t)b*T_*3;
  float y0v = fmaf(ya0, xb[0], fmaf(ya1, xb[1], fmaf(ya2, xb[2], ya3)));
  if (w == 0) ybuf[0][yc] = (_Float16)fmaxf(y0v, 0.f);
  float xs0 = xb[3], xs1 = xb[4], xs2 = xb[5];
  float xn0 = xb[6], xn1 = xb[7], xn2 = xb[8];

  float cA = c0[(size_t)b*H_ + kkA];                // replicated across quad
  float cB = c0[(size_t)b*H_ + kkB];
  if (w == 0){
    hbuf[0][kkA] = (_Float16)h0[(size_t)b*H_ + kkA];
    hbuf[0][kkB] = (_Float16)h0[(size_t)b*H_ + kkB];
  }
  __syncthreads();

  #pragma unroll 2
  for (int step=0; step<T_; ++step){
    int p = step & 1;                               // const-folded per unrolled copy
    const _Float16* hb = &hbuf[p][w*32];
    uint4 hv0 = *(const uint4*)(hb);
    uint4 hv1 = *(const uint4*)(hb + 8);
    uint4 hv2 = *(const uint4*)(hb + 16);
    uint4 hv3 = *(const uint4*)(hb + 24);
    const _Float16* yb = &ybuf[p][w*16];
    uint4 yv0 = *(const uint4*)(yb);
    uint4 yv1 = *(const uint4*)(yb + 8);
    // produce y[step+1]
    float yn = fmaf(ya0, xs0, fmaf(ya1, xs1, fmaf(ya2, xs2, ya3)));
    if (w == 0) ybuf[1-p][yc] = (_Float16)fmaxf(yn, 0.f);
    // advance scalar x pipeline
    xs0=xn0; xs1=xn1; xs2=xn2;
    { int t3 = (step+3 < T_) ? step+3 : T_-1;
      const float* xp = xb + 3*t3; xn0=xp[0]; xn1=xp[1]; xn2=xp[2]; }
    // dots: 8 rows x (32 h + 16 y) window
    float a[8] = {0,0,0,0,0,0,0,0};
    {
      uint4 hv[4] = {hv0, hv1, hv2, hv3};
      #pragma unroll
      for (int i=0;i<4;++i){
        half2_t h0_ = bc2(hv[i].x), h1_ = bc2(hv[i].y), h2_ = bc2(hv[i].z), h3_ = bc2(hv[i].w);
        #pragma unroll
        for (int r=0;r<8;++r){
          a[r] = fdot2(wh[r][4*i+0], h0_, a[r]);
          a[r] = fdot2(wh[r][4*i+1], h1_, a[r]);
          a[r] = fdot2(wh[r][4*i+2], h2_, a[r]);
          a[r] = fdot2(wh[r][4*i+3], h3_, a[r]);
        }
      }
      uint4 yv[2] = {yv0, yv1};
      #pragma unroll
      for (int i=0;i<2;++i){
        half2_t y0_ = bc2(yv[i].x), y1_ = bc2(yv[i].y), y2_ = bc2(yv[i].z), y3_ = bc2(yv[i].w);
        #pragma unroll
        for (int r=0;r<8;++r){
          a[r] = fdot2(wy[r][4*i+0], y0_, a[r]);
          a[r] = fdot2(wy[r][4*i+1], y1_, a[r]);
          a[r] = fdot2(wy[r][4*i+2], y2_, a[r]);
          a[r] = fdot2(wy[r][4*i+3], y3_, a[r]);
        }
      }
    }
    // reduce-scatter over quad: L1 (xor1, keep row parity = w&1)
    float b0,b1,b2,b3;
    {
      float s0 = o1 ? a[0] : a[1];  float k0 = o1 ? a[1] : a[0];
      float s1 = o1 ? a[2] : a[3];  float k1 = o1 ? a[3] : a[2];
      float s2 = o1 ? a[4] : a[5];  float k2 = o1 ? a[5] : a[4];
      float s3 = o1 ? a[6] : a[7];  float k3 = o1 ? a[7] : a[6];
      b0 = k0 + qperm<0xB1>(s0);
      b1 = k1 + qperm<0xB1>(s1);
      b2 = k2 + qperm<0xB1>(s2);
      b3 = k3 + qperm<0xB1>(s3);
    }
    // L2 (xor2, keep row bit1 = w&2): accA = row (w&3) of k=g ; accB = row 4+(w&3) of k=64+g
    float accA, accB;
    {
      float s0 = o2 ? b0 : b1;  float k0 = o2 ? b1 : b0;
      float s1 = o2 ? b2 : b3;  float k1 = o2 ? b3 : b2;
      accA = k0 + qperm<0x4E>(s0);
      accB = k1 + qperm<0x4E>(s1);
    }
    float biasA = o1 ? (o2 ? bias[3] : bias[1]) : (o2 ? bias[2] : bias[0]);
    float biasB = o1 ? (o2 ? bias[7] : bias[5]) : (o2 ? bias[6] : bias[4]);
    // lane w activates gate w for both k's
    float vA = accA + biasA;
    float vB = accB + biasB;
    float eA = __builtin_amdgcn_exp2f(S * vA);
    float eB = __builtin_amdgcn_exp2f(S * vB);
    float actA = fmaf(Bb, __builtin_amdgcn_rcpf(1.f + eA), Aa);
    float actB = fmaf(Bb, __builtin_amdgcn_rcpf(1.f + eB), Aa);
    // recombine k=g: c' = I*G + F*c ; h = O*tanh(c')
    float bpA = qperm<0x4E>(actA);
    float ppA = actA * (o1 ? cA : bpA);
    float cpA = ppA + qperm<0xB1>(ppA);
    cpA = qperm<0x00>(cpA);
    cA = cpA;
    float e2A = __builtin_amdgcn_exp2f(2.8853900817779268f * cpA);
    float thA = fmaf(-2.f, __builtin_amdgcn_rcpf(1.f + e2A), 1.f);
    float dA  = qperm<0x1B>(actA);
    float hA  = thA * dA;
    // recombine k=64+g
    float bpB = qperm<0x4E>(actB);
    float ppB = actB * (o1 ? cB : bpB);
    float cpB = ppB + qperm<0xB1>(ppB);
    cpB = qperm<0x00>(cpB);
    cB = cpB;
    float e2B = __builtin_amdgcn_exp2f(2.8853900817779268f * cpB);
    float thB = fmaf(-2.f, __builtin_amdgcn_rcpf(1.f + e2B), 1.f);
    float dB  = qperm<0x1B>(actB);
    float hB  = thB * dB;
    if (w == 0){
      hbuf[1-p][kkA] = (_Float16)hA;
      hbuf[1-p][kkB] = (_Float16)hB;
    }
    __syncthreads();
  }
  // classifier epilogue on final h (T even -> buffer 0)
  if (t < NCLS_){
    float s = out_b[t];
    #pragma unroll 8
    for (int kk=0; kk<H_; ++kk)
      s = fmaf(out_w[t*H_ + kk], (float)hbuf[0][kk], s);
    out[(size_t)b*NCLS_ + t] = s;
  }
}

extern "C" void kernel_launch(void* const* d_in, const int* in_sizes, int n_in,
                              void* d_out, int out_size, void* d_ws, size_t ws_size,
                              hipStream_t stream){
  const float* x      = (const float*)d_in[0];
  const float* conv_w = (const float*)d_in[1];
  // d_in[2] = conv_b: cancels exactly inside BN(train stats) — unused
  const float* bn_g   = (const float*)d_in[3];
  const float* bn_b   = (const float*)d_in[4];
  const float* w_ih   = (const float*)d_in[5];
  const float* b_ih   = (const float*)d_in[6];
  const float* w_hh   = (const float*)d_in[7];
  const float* b_hh   = (const float*)d_in[8];
  const float* out_w  = (const float*)d_in[9];
  const float* out_b  = (const float*)d_in[10];
  const float* h0     = (const float*)d_in[11];
  const float* c0     = (const float*)d_in[12];
  float* out   = (float*)d_out;
  float* stats = (float*)d_ws;

  hipMemsetAsync(d_ws, 0, 64, stream);
  stats_kernel<<<256, 256, 0, stream>>>(x, stats);
  lstm_kernel<<<B_, 256, 0, stream>>>(x, conv_w, bn_g, bn_b, stats,
                                      w_ih, b_ih, b_hh, w_hh, h0, c0, out_w, out_b, out);
}

// Round 5
// 2419.131 us; speedup vs baseline: 1.1178x; 1.1178x over previous
//
#include <hip/hip_runtime.h>
#include <cstdint>
#include <cstddef>

// Problem dims (fixed by reference)
#define B_    64
#define T_    4096
#define H_    128
#define C1_   64
#define NCLS_ 40

#define LOG2E_    1.4426950408889634f
#define TWOLOG2E_ 2.8853900817779268f

typedef _Float16 half2_t __attribute__((ext_vector_type(2)));

__device__ __forceinline__ float fdot2(half2_t a, half2_t b, float c){
#if defined(__has_builtin) && __has_builtin(__builtin_amdgcn_fdot2)
  return __builtin_amdgcn_fdot2(a, b, c, false);   // v_dot2_f32_f16, full-rate
#else
  return fmaf((float)a.x, (float)b.x, fmaf((float)a.y, (float)b.y, c));
#endif
}
__device__ __forceinline__ half2_t bc2(unsigned int u){ return __builtin_bit_cast(half2_t, u); }
__device__ __forceinline__ half2_t pack2(float a, float b){
  half2_t r; r.x = (_Float16)a; r.y = (_Float16)b; return r;   // RTNE
}

// quad_perm DPP (VALU pipe). ctrl = l0|l1<<2|l2<<4|l3<<6
template<int CTRL>
__device__ __forceinline__ float qperm(float x){
  return __int_as_float(__builtin_amdgcn_update_dpp(0, __float_as_int(x), CTRL, 0xF, 0xF, true));
}

// ---------------- kernel 1: 3x3 second-moment stats of x over B*T ----------------
__global__ __launch_bounds__(256) void stats_kernel(const float* __restrict__ x,
                                                    float* __restrict__ stats){
  int t = blockIdx.x * 256 + threadIdx.x;
  const float4* xv = (const float4*)x + (size_t)t * 3;
  float4 a = xv[0], b = xv[1], c = xv[2];
  float x0[4] = {a.x, a.w, b.z, c.y};
  float x1[4] = {a.y, b.x, b.w, c.z};
  float x2[4] = {a.z, b.y, c.x, c.w};
  float s[9] = {0,0,0,0,0,0,0,0,0};
  #pragma unroll
  for (int r=0;r<4;++r){
    s[0]+=x0[r]; s[1]+=x1[r]; s[2]+=x2[r];
    s[3]+=x0[r]*x0[r]; s[4]+=x0[r]*x1[r]; s[5]+=x0[r]*x2[r];
    s[6]+=x1[r]*x1[r]; s[7]+=x1[r]*x2[r]; s[8]+=x2[r]*x2[r];
  }
  __shared__ float red[9][256];
  #pragma unroll
  for (int j=0;j<9;++j) red[j][threadIdx.x] = s[j];
  __syncthreads();
  if (threadIdx.x < 9){
    float sum = 0.f;
    for (int i=0;i<256;++i) sum += red[threadIdx.x][i];
    atomicAdd(&stats[threadIdx.x], sum);
  }
}

// Fold conv + BN(train stats) + gamma/beta into per-channel affine. conv_b cancels.
__device__ __forceinline__ void chan_affine(int c, const float* __restrict__ conv_w,
    const float* __restrict__ bn_g, const float* __restrict__ bn_b,
    const float* __restrict__ stats,
    float& A0, float& A1, float& A2, float& Bc){
  const float Ninv = 1.0f / (float)(B_*T_);
  float m0=stats[0]*Ninv, m1=stats[1]*Ninv, m2=stats[2]*Ninv;
  float c00=stats[3]*Ninv-m0*m0, c01=stats[4]*Ninv-m0*m1, c02=stats[5]*Ninv-m0*m2;
  float c11=stats[6]*Ninv-m1*m1, c12=stats[7]*Ninv-m1*m2, c22=stats[8]*Ninv-m2*m2;
  float w0=conv_w[c*3+0], w1=conv_w[c*3+1], w2=conv_w[c*3+2];
  float var = w0*(w0*c00 + 2.f*(w1*c01 + w2*c02)) + w1*(w1*c11 + 2.f*w2*c12) + w2*w2*c22;
  float sc = bn_g[c] * rsqrtf(var + 1e-5f);
  A0 = w0*sc; A1 = w1*sc; A2 = w2*sc;
  Bc = bn_b[c] - (w0*m0 + w1*m1 + w2*m2)*sc;
}

// ---------------- kernel 2 (Tier A): y = relu(affine(x)) as f16 [B][T][64] ----------------
__global__ __launch_bounds__(256) void y_kernel(const float* __restrict__ x,
    const float* __restrict__ conv_w, const float* __restrict__ bn_g,
    const float* __restrict__ bn_b, const float* __restrict__ stats,
    _Float16* __restrict__ yg){
  __shared__ float4 coef[C1_];
  int tid = threadIdx.x;
  if (tid < C1_){
    float A0,A1,A2,Bc; chan_affine(tid, conv_w, bn_g, bn_b, stats, A0,A1,A2,Bc);
    coef[tid] = make_float4(A0,A1,A2,Bc);
  }
  __syncthreads();
  size_t idx = (size_t)blockIdx.x * 256 + tid;      // (b*T + t)
  const float* xp = x + idx*3;
  float x0 = xp[0], x1 = xp[1], x2 = xp[2];
  unsigned int ob[32];
  #pragma unroll
  for (int c=0; c<C1_; c+=2){
    float4 c0 = coef[c], c1 = coef[c+1];
    float v0 = fmaxf(fmaf(c0.x,x0, fmaf(c0.y,x1, fmaf(c0.z,x2, c0.w))), 0.f);
    float v1 = fmaxf(fmaf(c1.x,x0, fmaf(c1.y,x1, fmaf(c1.z,x2, c1.w))), 0.f);
    ob[c>>1] = __builtin_bit_cast(unsigned int, pack2(v0, v1));
  }
  uint4* dst = (uint4*)(yg + idx*C1_);
  #pragma unroll
  for (int i=0;i<8;++i) dst[i] = ((uint4*)ob)[i];
}

// ---------------- kernel 3: persistent per-batch LSTM ----------------
// 64 blocks x 512 threads (8 waves, 2/SIMD). thread t: k=t>>2, w=t&3 (32-wide h
// window / 16-wide y window). Pre-barrier: y-dots (y available 1 step early) +
// y prefetch/production. Raw s_barrier + manual lgkmcnt(0) (vmcnt stays in flight).
// Gate exp2-scales folded into weights/bias; c carried scaled by 2log2e.
template<bool YG>
__global__ __launch_bounds__(512,2) void lstm_kernel(
    const _Float16* __restrict__ yg, const float* __restrict__ x,
    const float* __restrict__ conv_w, const float* __restrict__ bn_g,
    const float* __restrict__ bn_b, const float* __restrict__ stats,
    const float* __restrict__ w_ih, const float* __restrict__ b_ih,
    const float* __restrict__ b_hh, const float* __restrict__ w_hh,
    const float* __restrict__ h0, const float* __restrict__ c0,
    const float* __restrict__ out_w, const float* __restrict__ out_b,
    float* __restrict__ out){
  int b = blockIdx.x, t = threadIdx.x;
  int k = t >> 2, w = t & 3;
  __shared__ __align__(16) _Float16 hbuf[2][H_];
  __shared__ __align__(16) _Float16 ybuf[4][C1_];   // Tier B mod-4 ring

  // weights prescaled by gate exp2-scale: sg = -log2e (I,F,O), +2log2e (G)
  half2_t wh[4][16];
  half2_t wy[4][8];
  #pragma unroll
  for (int g=0; g<4; ++g){
    float sg = (g==2) ? TWOLOG2E_ : -LOG2E_;
    const float4* p = (const float4*)(w_hh + (size_t)(g*H_ + k)*H_ + w*32);
    #pragma unroll
    for (int i=0;i<8;++i){
      float4 v = p[i];
      wh[g][2*i]   = pack2(sg*v.x, sg*v.y);
      wh[g][2*i+1] = pack2(sg*v.z, sg*v.w);
    }
    const float4* py = (const float4*)(w_ih + (size_t)(g*H_ + k)*C1_ + w*16);
    #pragma unroll
    for (int i=0;i<4;++i){
      float4 v = py[i];
      wy[g][2*i]   = pack2(sg*v.x, sg*v.y);
      wy[g][2*i+1] = pack2(sg*v.z, sg*v.w);
    }
  }
  float biasSel;
  { float sg = (w==2) ? TWOLOG2E_ : -LOG2E_;
    biasSel = sg * (b_ih[w*H_+k] + b_hh[w*H_+k]); }
  // lane activation: act = Aa + Bb*rcp(1+exp2(v_scaled)); I is carried pre-scaled by 2log2e
  float Aa = (w==2) ?  1.f : 0.f;
  float Bb = (w==0) ? TWOLOG2E_ : ((w==2) ? -2.f : 1.f);
  bool o1 = (w & 1) != 0;
  bool o2 = (w & 2) != 0;

  float cs = TWOLOG2E_ * c0[(size_t)b*H_ + k];      // scaled cell state (lanes 0,1 authoritative)
  if (w == 0) hbuf[0][k] = (_Float16)h0[(size_t)b*H_ + k];

  // ---- Tier B (in-kernel y) setup ----
  int yc = t >> 3; bool prod = ((t & 7) == 0);
  float ya0=0, ya1=0, ya2=0, ya3=0;
  float xs0=0, xs1=0, xs2=0, xn0=0, xn1=0, xn2=0;
  const float* xb = x + (size_t)b*T_*3;
  if constexpr (!YG){
    chan_affine(yc, conv_w, bn_g, bn_b, stats, ya0, ya1, ya2, ya3);
    if (prod){
      float v0 = fmaf(ya0, xb[0], fmaf(ya1, xb[1], fmaf(ya2, xb[2], ya3)));
      float v1 = fmaf(ya0, xb[3], fmaf(ya1, xb[4], fmaf(ya2, xb[5], ya3)));
      ybuf[0][yc] = (_Float16)fmaxf(v0, 0.f);
      ybuf[1][yc] = (_Float16)fmaxf(v1, 0.f);
    }
    xs0 = xb[6];  xs1 = xb[7];  xs2 = xb[8];        // x[2]
    xn0 = xb[9];  xn1 = xb[10]; xn2 = xb[11];       // x[3]
  }
  // ---- Tier A y preload ----
  const _Float16* ygb = nullptr;
  uint4 yreg[2][2];
  if constexpr (YG){
    ygb = yg + (size_t)b*T_*C1_ + w*16;
    yreg[0][0] = *(const uint4*)(ygb);
    yreg[0][1] = *(const uint4*)(ygb + 8);
  }
  __syncthreads();

  #pragma unroll 2
  for (int step=0; step<T_; ++step){
    int p = step & 1;
    float acc[4] = {0.f,0.f,0.f,0.f};
    // ===== pre-barrier: y-dots for THIS step + next-y prefetch/production =====
    if constexpr (YG){
      uint4 yv0 = yreg[p][0], yv1 = yreg[p][1];
      half2_t y0_ = bc2(yv0.x), y1_ = bc2(yv0.y), y2_ = bc2(yv0.z), y3_ = bc2(yv0.w);
      half2_t y4_ = bc2(yv1.x), y5_ = bc2(yv1.y), y6_ = bc2(yv1.z), y7_ = bc2(yv1.w);
      #pragma unroll
      for (int g=0; g<4; ++g){
        acc[g] = fdot2(wy[g][0], y0_, acc[g]);
        acc[g] = fdot2(wy[g][1], y1_, acc[g]);
        acc[g] = fdot2(wy[g][2], y2_, acc[g]);
        acc[g] = fdot2(wy[g][3], y3_, acc[g]);
        acc[g] = fdot2(wy[g][4], y4_, acc[g]);
        acc[g] = fdot2(wy[g][5], y5_, acc[g]);
        acc[g] = fdot2(wy[g][6], y6_, acc[g]);
        acc[g] = fdot2(wy[g][7], y7_, acc[g]);
      }
      int tn = (step+1 < T_) ? step+1 : step;
      const _Float16* ypd = ygb + (size_t)tn*C1_;
      yreg[1-p][0] = *(const uint4*)(ypd);          // vmcnt domain; waits land next iter
      yreg[1-p][1] = *(const uint4*)(ypd + 8);
    } else {
      const _Float16* yb2 = &ybuf[step & 3][w*16];  // written >=2 barriers ago
      uint4 yv0 = *(const uint4*)(yb2);
      uint4 yv1 = *(const uint4*)(yb2 + 8);
      half2_t y0_ = bc2(yv0.x), y1_ = bc2(yv0.y), y2_ = bc2(yv0.z), y3_ = bc2(yv0.w);
      half2_t y4_ = bc2(yv1.x), y5_ = bc2(yv1.y), y6_ = bc2(yv1.z), y7_ = bc2(yv1.w);
      #pragma unroll
      for (int g=0; g<4; ++g){
        acc[g] = fdot2(wy[g][0], y0_, acc[g]);
        acc[g] = fdot2(wy[g][1], y1_, acc[g]);
        acc[g] = fdot2(wy[g][2], y2_, acc[g]);
        acc[g] = fdot2(wy[g][3], y3_, acc[g]);
        acc[g] = fdot2(wy[g][4], y4_, acc[g]);
        acc[g] = fdot2(wy[g][5], y5_, acc[g]);
        acc[g] = fdot2(wy[g][6], y6_, acc[g]);
        acc[g] = fdot2(wy[g][7], y7_, acc[g]);
      }
      float yn = fmaf(ya0, xs0, fmaf(ya1, xs1, fmaf(ya2, xs2, ya3)));
      if (prod) ybuf[(step+2) & 3][yc] = (_Float16)fmaxf(yn, 0.f);   // y[step+2]
      xs0=xn0; xs1=xn1; xs2=xn2;
      { int t4 = (step+4 < T_) ? step+4 : T_-1;
        const float* xp = xb + 3*t4; xn0=xp[0]; xn1=xp[1]; xn2=xp[2]; }
    }
    // ===== barrier (LDS-only drain; vmcnt loads stay in flight) =====
    asm volatile("s_waitcnt lgkmcnt(0)" ::: "memory");
    __builtin_amdgcn_s_barrier();
    asm volatile("" ::: "memory");
    // ===== post-barrier: h-dots =====
    const _Float16* hb = &hbuf[p][w*32];
    #pragma unroll
    for (int i=0;i<4;++i){
      uint4 hv = *(const uint4*)(hb + 8*i);
      half2_t h0_ = bc2(hv.x), h1_ = bc2(hv.y), h2_ = bc2(hv.z), h3_ = bc2(hv.w);
      #pragma unroll
      for (int g=0; g<4; ++g){
        acc[g] = fdot2(wh[g][4*i+0], h0_, acc[g]);
        acc[g] = fdot2(wh[g][4*i+1], h1_, acc[g]);
        acc[g] = fdot2(wh[g][4*i+2], h2_, acc[g]);
        acc[g] = fdot2(wh[g][4*i+3], h3_, acc[g]);
      }
    }
    // reduce-scatter over quad: lane w ends with gate w's total
    float b01, b23;
    { float s0 = o1 ? acc[0] : acc[1];  float k0 = o1 ? acc[1] : acc[0];
      float s1 = o1 ? acc[2] : acc[3];  float k1 = o1 ? acc[3] : acc[2];
      b01 = k0 + qperm<0xB1>(s0);
      b23 = k1 + qperm<0xB1>(s1); }
    float accv;
    { float s = o2 ? b01 : b23;  float kk = o2 ? b23 : b01;
      accv = kk + qperm<0x4E>(s); }
    // activation (prescaled): act = Aa + Bb*rcp(1+exp2(v))
    float v = accv + biasSel;
    float e = __builtin_amdgcn_exp2f(v);
    float act = fmaf(Bb, __builtin_amdgcn_rcpf(1.f + e), Aa);
    // recombine: cs' = I_s*G + F*cs (lanes 0,1); h = tanh(c')*O (lane 0)
    float dA = qperm<0x1B>(act);                    // lane0 <- O
    float bp = qperm<0x4E>(act);                    // lane0 <- G
    float pp = act * (o1 ? cs : bp);                // lane0: I_s*G ; lane1: F*cs
    float cps = pp + qperm<0xB1>(pp);               // lanes 0,1: scaled c'
    cs = cps;
    float th = fmaf(-2.f, __builtin_amdgcn_rcpf(1.f + __builtin_amdgcn_exp2f(cps)), 1.f);
    float h = th * dA;
    if (w == 0) hbuf[1-p][k] = (_Float16)h;
  }
  __syncthreads();
  // classifier epilogue on final h (T even -> buffer 0)
  if (t < NCLS_){
    float s = out_b[t];
    #pragma unroll 8
    for (int kk=0; kk<H_; ++kk)
      s = fmaf(out_w[t*H_ + kk], (float)hbuf[0][kk], s);
    out[(size_t)b*NCLS_ + t] = s;
  }
}

extern "C" void kernel_launch(void* const* d_in, const int* in_sizes, int n_in,
                              void* d_out, int out_size, void* d_ws, size_t ws_size,
                              hipStream_t stream){
  const float* x      = (const float*)d_in[0];
  const float* conv_w = (const float*)d_in[1];
  // d_in[2] = conv_b: cancels exactly inside BN(train stats) — unused
  const float* bn_g   = (const float*)d_in[3];
  const float* bn_b   = (const float*)d_in[4];
  const float* w_ih   = (const float*)d_in[5];
  const float* b_ih   = (const float*)d_in[6];
  const float* w_hh   = (const float*)d_in[7];
  const float* b_hh   = (const float*)d_in[8];
  const float* out_w  = (const float*)d_in[9];
  const float* out_b  = (const float*)d_in[10];
  const float* h0     = (const float*)d_in[11];
  const float* c0     = (const float*)d_in[12];
  float* out      = (float*)d_out;
  float* stats    = (float*)d_ws;
  _Float16* yg    = (_Float16*)((char*)d_ws + 4096);
  const size_t needA = 4096 + (size_t)B_*T_*C1_*sizeof(_Float16);   // ~33.6 MB

  hipMemsetAsync(d_ws, 0, 64, stream);
  stats_kernel<<<256, 256, 0, stream>>>(x, stats);
  if (ws_size >= needA){
    y_kernel<<<(B_*T_)/256, 256, 0, stream>>>(x, conv_w, bn_g, bn_b, stats, yg);
    lstm_kernel<true><<<B_, 512, 0, stream>>>(yg, x, conv_w, bn_g, bn_b, stats,
                                              w_ih, b_ih, b_hh, w_hh, h0, c0, out_w, out_b, out);
  } else {
    lstm_kernel<false><<<B_, 512, 0, stream>>>(yg, x, conv_w, bn_g, bn_b, stats,
                                               w_ih, b_ih, b_hh, w_hh, h0, c0, out_w, out_b, out);
  }
}